// Round 1
// baseline (507.571 us; speedup 1.0000x reference)
//
#include <hip/hip_runtime.h>
#include <hip/hip_bf16.h>
#include <math.h>

#define B_ 64
#define S_ 2048
#define D_ 512
#define A_ 512

typedef __attribute__((ext_vector_type(8))) short short8;
typedef __attribute__((ext_vector_type(4))) short short4b;
typedef __attribute__((ext_vector_type(4))) float f32x4;

__device__ __forceinline__ short bf16b(float f) {
    __hip_bfloat16 h = __float2bfloat16(f);
    union { __hip_bfloat16 h; short s; } u; u.h = h;
    return u.s;
}

__device__ __forceinline__ float tanh_fast(float x) {
    float e = __expf(2.0f * x);
    return 1.0f - 2.0f / (e + 1.0f);
}

// async global->LDS, 16B per lane; LDS dest = base + lane*16 (wave-uniform base)
__device__ __forceinline__ void llds16(const void* g, void* l) {
    __builtin_amdgcn_global_load_lds(
        (const __attribute__((address_space(1))) unsigned int*)g,
        (__attribute__((address_space(3))) unsigned int*)l, 16, 0, 0);
}

// ---------------------------------------------------------------------------
// Kernel 1: htWb[b][a] = sum_d input[b][d] * Wh[d][a] + b_attn[a]   (fp32)
// ---------------------------------------------------------------------------
__global__ __launch_bounds__(256) void k_htw(const float* __restrict__ input,
                                             const float* __restrict__ Wh,
                                             const float* __restrict__ b_attn,
                                             float* __restrict__ htWb) {
    __shared__ float xin[512];
    const int b = blockIdx.x, t = threadIdx.x;
    xin[t] = input[b * D_ + t];
    xin[t + 256] = input[b * D_ + t + 256];
    __syncthreads();
    float a0 = 0.f, a1 = 0.f;
#pragma unroll 8
    for (int d = 0; d < D_; ++d) {
        const float xv = xin[d];
        a0 += xv * Wh[d * A_ + t];
        a1 += xv * Wh[d * A_ + t + 256];
    }
    htWb[b * A_ + t] = a0 + b_attn[t];
    htWb[b * A_ + t + 256] = a1 + b_attn[t + 256];
}

// ---------------------------------------------------------------------------
// Kernel 2: WsT[a][k] = bf16(Ws[k][a])   (transpose + convert, 64x64 tiles)
// ---------------------------------------------------------------------------
__global__ __launch_bounds__(256) void k_wst(const float* __restrict__ Ws,
                                             short* __restrict__ WsT) {
    const int bx = blockIdx.x & 7, by = blockIdx.x >> 3;
    const int r0 = by * 64, c0 = bx * 64;  // r = k (D dim), c = a (A dim)
    __shared__ short tile[64][72];
    const int t = threadIdx.x;
    const int row = t >> 4, col4 = (t & 15) * 4;
#pragma unroll
    for (int i = 0; i < 4; ++i) {
        const float4 v = *(const float4*)&Ws[(r0 + row + i * 16) * A_ + c0 + col4];
        tile[col4 + 0][row + i * 16] = bf16b(v.x);
        tile[col4 + 1][row + i * 16] = bf16b(v.y);
        tile[col4 + 2][row + i * 16] = bf16b(v.z);
        tile[col4 + 3][row + i * 16] = bf16b(v.w);
    }
    __syncthreads();
#pragma unroll
    for (int i = 0; i < 4; ++i) {
        const int arow = row + i * 16;
        short4b o;
        o.x = tile[arow][col4 + 0];
        o.y = tile[arow][col4 + 1];
        o.z = tile[arow][col4 + 2];
        o.w = tile[arow][col4 + 3];
        *(short4b*)&WsT[(c0 + arow) * D_ + r0 + col4] = o;
    }
}

// ---------------------------------------------------------------------------
// Kernel 3: scores[b][s] = sum_a va[a]*tanh(htWb[b][a] + sum_d ctx[b][s][d]*Ws[d][a])
//   tile: 64 rows x 512 cols, BK=32, bf16 MFMA 16x16x32, fp32 epilogue.
//   Also computes row-sum of ctx for the padding mask.
// ---------------------------------------------------------------------------
__global__ __launch_bounds__(512, 4)
void k_score(const float* __restrict__ ctx, const short* __restrict__ WsT,
             const float* __restrict__ htWb, const float* __restrict__ va,
             float* __restrict__ scores) {
    __shared__ __align__(16) short Ab[2][64 * 32];    // [row][k] swizzled, 4KB each
    __shared__ __align__(16) short Bb[2][512 * 32];   // [a][k]  swizzled, 32KB each
    __shared__ float hv_s[512];
    __shared__ float va_s[512];
    __shared__ float scores_s[64];
    __shared__ float rowsum_s[64];

    const int tid = threadIdx.x;
    const int w = tid >> 6, lane = tid & 63;
    const int wm = w >> 2, wn = w & 3;
    const int tile = blockIdx.x;
    const int b = tile >> 5;            // 32 tiles of 64 rows per batch
    const int s0 = (tile & 31) * 64;
    const long rowbase = (long)b * S_ + s0;

    hv_s[tid] = htWb[b * A_ + tid];
    va_s[tid] = va[tid];
    if (tid < 64) scores_s[tid] = 0.f;

    // --- A staging (reg -> cvt -> swizzled ds_write), one float4 per thread per K-step
    const int arow = tid >> 3, kq = tid & 7;
    const float* aSrc = ctx + (rowbase + arow) * D_ + kq * 4;
    float rowsum_acc = 0.f;

    f32x4 acc[2][8];
#pragma unroll
    for (int i = 0; i < 2; ++i)
#pragma unroll
        for (int j = 0; j < 8; ++j)
#pragma unroll
            for (int e = 0; e < 4; ++e) acc[i][j][e] = 0.f;

#define STAGE_B(buf, kt)                                                      \
    {                                                                         \
        _Pragma("unroll") for (int j = 0; j < 4; ++j) {                       \
            const int a = (w * 4 + j) * 16 + (lane >> 2);                     \
            const int c = lane & 3;                                           \
            const int csw = c ^ ((a >> 1) & 3);                               \
            llds16(WsT + a * D_ + (kt) * 32 + csw * 8,                        \
                   (void*)&Bb[buf][(w * 4 + j) * 512]);                       \
        }                                                                     \
    }

#define STAGE_A_WRITE(buf, v)                                                 \
    {                                                                         \
        rowsum_acc += (v).x + (v).y + (v).z + (v).w;                          \
        short4b o;                                                            \
        o.x = bf16b((v).x); o.y = bf16b((v).y);                               \
        o.z = bf16b((v).z); o.w = bf16b((v).w);                               \
        const int cw = kq >> 1, sub = kq & 1;                                 \
        const int csw = cw ^ ((arow >> 1) & 3);                               \
        *(short4b*)((char*)&Ab[buf][0] + arow * 64 + csw * 16 + sub * 8) = o; \
    }

    // prologue: stage tile 0
    STAGE_B(0, 0);
    {
        const float4 v = *(const float4*)(aSrc);
        STAGE_A_WRITE(0, v);
    }
    __syncthreads();

    for (int kt = 0; kt < 16; ++kt) {
        const int cur = kt & 1;
        float4 nv;
        if (kt < 15) {
            nv = *(const float4*)(aSrc + (kt + 1) * 32);
            STAGE_B(cur ^ 1, kt + 1);
        }
        // compute from buf[cur]
        {
            short8 af[2];
#pragma unroll
            for (int mf = 0; mf < 2; ++mf) {
                const int r = wm * 32 + mf * 16 + (lane & 15);
                const int c = lane >> 4;
                const int csw = c ^ ((r >> 1) & 3);
                af[mf] = *(const short8*)((const char*)&Ab[cur][0] + r * 64 + csw * 16);
            }
#pragma unroll
            for (int nf = 0; nf < 8; ++nf) {
                const int a = wn * 128 + nf * 16 + (lane & 15);
                const int c = lane >> 4;
                const int csw = c ^ ((a >> 1) & 3);
                const short8 bf =
                    *(const short8*)((const char*)&Bb[cur][0] + a * 64 + csw * 16);
                acc[0][nf] = __builtin_amdgcn_mfma_f32_16x16x32_bf16(af[0], bf, acc[0][nf], 0, 0, 0);
                acc[1][nf] = __builtin_amdgcn_mfma_f32_16x16x32_bf16(af[1], bf, acc[1][nf], 0, 0, 0);
            }
        }
        if (kt < 15) STAGE_A_WRITE(cur ^ 1, nv);
        __syncthreads();
    }

    // padding-mask row sums (8 threads per row -> lane group reduce)
    rowsum_acc += __shfl_xor(rowsum_acc, 1);
    rowsum_acc += __shfl_xor(rowsum_acc, 2);
    rowsum_acc += __shfl_xor(rowsum_acc, 4);
    if ((tid & 7) == 0) rowsum_s[arow] = rowsum_acc;

    // epilogue: score_row = sum_a va[a]*tanh(htWb[a] + acc)
    float hv[8], vv[8];
#pragma unroll
    for (int nf = 0; nf < 8; ++nf) {
        const int col = wn * 128 + nf * 16 + (lane & 15);
        hv[nf] = hv_s[col];
        vv[nf] = va_s[col];
    }
#pragma unroll
    for (int mf = 0; mf < 2; ++mf) {
#pragma unroll
        for (int r = 0; r < 4; ++r) {
            float p = 0.f;
#pragma unroll
            for (int nf = 0; nf < 8; ++nf)
                p += vv[nf] * tanh_fast(hv[nf] + acc[mf][nf][r]);
            p += __shfl_xor(p, 1);
            p += __shfl_xor(p, 2);
            p += __shfl_xor(p, 4);
            p += __shfl_xor(p, 8);
            if ((lane & 15) == 0) {
                const int row = wm * 32 + mf * 16 + (lane >> 4) * 4 + r;
                atomicAdd(&scores_s[row], p);
            }
        }
    }
    __syncthreads();

    if (tid < 64) {
        float sc = scores_s[tid];
        if (rowsum_s[tid] == 0.0f) sc = -__builtin_inff();
        scores[rowbase + tid] = sc;
    }
}

// ---------------------------------------------------------------------------
// Kernel 4: in-place softmax over S per batch row (scores -> attn_dist)
// ---------------------------------------------------------------------------
__global__ __launch_bounds__(256) void k_softmax(float* __restrict__ dist) {
    const int b = blockIdx.x, t = threadIdx.x;
    float* p = dist + b * S_;
    float v[8];
    float m = -__builtin_inff();
#pragma unroll
    for (int i = 0; i < 8; ++i) {
        v[i] = p[t + i * 256];
        m = fmaxf(m, v[i]);
    }
#pragma unroll
    for (int mask = 1; mask < 64; mask <<= 1) m = fmaxf(m, __shfl_xor(m, mask));
    __shared__ float redm[4], reds[4];
    if ((t & 63) == 0) redm[t >> 6] = m;
    __syncthreads();
    m = fmaxf(fmaxf(redm[0], redm[1]), fmaxf(redm[2], redm[3]));
    float sum = 0.f;
#pragma unroll
    for (int i = 0; i < 8; ++i) {
        v[i] = __expf(v[i] - m);
        sum += v[i];
    }
#pragma unroll
    for (int mask = 1; mask < 64; mask <<= 1) sum += __shfl_xor(sum, mask);
    if ((t & 63) == 0) reds[t >> 6] = sum;
    __syncthreads();
    sum = reds[0] + reds[1] + reds[2] + reds[3];
    const float inv = 1.0f / sum;
#pragma unroll
    for (int i = 0; i < 8; ++i) p[t + i * 256] = v[i] * inv;
}

// ---------------------------------------------------------------------------
// Kernel 5: partial[b][ch][d] = sum_{s in chunk} p[b][s] * ctx[b][s][d]
// ---------------------------------------------------------------------------
__global__ __launch_bounds__(256) void k_wsum(const float* __restrict__ ctx,
                                              const float* __restrict__ dist,
                                              float* __restrict__ partial) {
    const int ch = blockIdx.x, b = blockIdx.y;
    const int t = threadIdx.x;
    __shared__ float ps[128];
    if (t < 128) ps[t] = dist[b * S_ + ch * 128 + t];
    __syncthreads();
    const float* cbase = ctx + ((long)b * S_ + ch * 128) * D_;
    float ax = 0.f, ay = 0.f;
#pragma unroll 4
    for (int r = 0; r < 128; ++r) {
        const float2 cv = *(const float2*)&cbase[r * D_ + t * 2];
        ax += ps[r] * cv.x;
        ay += ps[r] * cv.y;
    }
    float2 o; o.x = ax; o.y = ay;
    *(float2*)&partial[((b * 16 + ch) * D_) + t * 2] = o;
}

// ---------------------------------------------------------------------------
// Kernel 6: attn_context[b][d] = sum_ch partial[b][ch][d]
// ---------------------------------------------------------------------------
__global__ __launch_bounds__(256) void k_reduce(const float* __restrict__ partial,
                                                float* __restrict__ out) {
    const int b = blockIdx.x, t = threadIdx.x;
    float ax = 0.f, ay = 0.f;
#pragma unroll
    for (int j = 0; j < 16; ++j) {
        const float2 v = *(const float2*)&partial[((b * 16 + j) * D_) + t * 2];
        ax += v.x;
        ay += v.y;
    }
    float2 o; o.x = ax; o.y = ay;
    *(float2*)&out[b * D_ + t * 2] = o;
}

// ---------------------------------------------------------------------------
extern "C" void kernel_launch(void* const* d_in, const int* in_sizes, int n_in,
                              void* d_out, int out_size, void* d_ws, size_t ws_size,
                              hipStream_t stream) {
    (void)in_sizes; (void)n_in; (void)out_size; (void)ws_size;
    const float* input  = (const float*)d_in[0];
    const float* ctx    = (const float*)d_in[1];
    const float* Wh     = (const float*)d_in[2];
    const float* Ws     = (const float*)d_in[3];
    const float* b_attn = (const float*)d_in[4];
    const float* va     = (const float*)d_in[5];

    float* out = (float*)d_out;
    float* attn_ctx  = out;              // [64, 512]
    float* attn_dist = out + B_ * D_;    // [64, 2048] (used for raw scores first)

    char* ws = (char*)d_ws;
    float* htWb    = (float*)ws;                          // 64*512*4   = 128 KB
    short* WsT     = (short*)(ws + 131072);               // 512*512*2  = 512 KB
    float* partial = (float*)(ws + 131072 + 524288);      // 64*16*512*4 = 2 MB

    k_htw<<<64, 256, 0, stream>>>(input, Wh, b_attn, htWb);
    k_wst<<<64, 256, 0, stream>>>(Ws, WsT);
    k_score<<<2048, 512, 0, stream>>>(ctx, WsT, htWb, va, attn_dist);
    k_softmax<<<64, 256, 0, stream>>>(attn_dist);
    k_wsum<<<dim3(16, 64), 256, 0, stream>>>(ctx, attn_dist, partial);
    k_reduce<<<64, 256, 0, stream>>>(partial, attn_ctx);
}